// Round 2
// baseline (596.868 us; speedup 1.0000x reference)
//
#include <hip/hip_runtime.h>
#include <cstdint>

#define NTOK 4096
#define CDIM 1024
#define DDIM 4096
#define NEXP 8
#define PAIR_CAP 9216
#define MAXTILE 72

typedef __bf16 bf16x8 __attribute__((ext_vector_type(8)));
typedef float f32x4 __attribute__((ext_vector_type(4)));
typedef unsigned int u32x4 __attribute__((ext_vector_type(4)));
typedef unsigned short u16;

__device__ __forceinline__ u16 bf16_rne(float f) {
  unsigned u = __builtin_bit_cast(unsigned, f);
  u += 0x7fffu + ((u >> 16) & 1u);
  return (u16)(u >> 16);
}
__device__ __forceinline__ unsigned pk2(float a, float b) {
  return (unsigned)bf16_rne(a) | ((unsigned)bf16_rne(b) << 16);
}
__device__ __forceinline__ float bf2f(u16 v) {
  unsigned u = (unsigned)v << 16;
  return __builtin_bit_cast(float, u);
}
__device__ __forceinline__ bf16x8 ldfrag(const u16* p) {
  u32x4 v = *(const u32x4*)p;
  return __builtin_bit_cast(bf16x8, v);
}
__device__ __forceinline__ float gelu_f(float v) {
  // tanh-GELU: v * sigmoid(1.5957691216*(v + 0.044715 v^3)); max |err| ~3e-4
  float u = v + 0.044715f * v * v * v;
  return v / (1.f + __expf(-1.5957691216f * u));
}

typedef __attribute__((address_space(1))) const unsigned int as1_u32;
typedef __attribute__((address_space(3))) unsigned int as3_u32;
__device__ __forceinline__ void gload_lds16(const void* g, void* l) {
  __builtin_amdgcn_global_load_lds((as1_u32*)g, (as3_u32*)l, 16, 0, 0);
}

// ---------------- fused prep: router + xcast + transpose(s) ----------------
__device__ __forceinline__ void transpose_tile(const float* __restrict__ src0,
                                               u16* __restrict__ dst0, int K, int N,
                                               int kb, int nb, int t, float tile[64][65]) {
  const float* src = src0 + (size_t)kb * N + nb;
#pragma unroll
  for (int j = 0; j < 4; ++j) {
    int idx4 = t + j * 256;  // 1024 float4 = 64x64 floats
    int r = idx4 >> 4, c4 = idx4 & 15;
    float4 v = *(const float4*)&src[(size_t)r * N + c4 * 4];
    tile[r][c4 * 4 + 0] = v.x; tile[r][c4 * 4 + 1] = v.y;
    tile[r][c4 * 4 + 2] = v.z; tile[r][c4 * 4 + 3] = v.w;
  }
  __syncthreads();
  u16* dst = dst0 + (size_t)nb * K + kb;
#pragma unroll
  for (int j = 0; j < 8; ++j) {
    int idxp = t + j * 256;  // 2048 x ushort2
    int n = idxp >> 5, kp = idxp & 31;
    *(unsigned*)&dst[(size_t)n * K + kp * 2] = pk2(tile[kp * 2][n], tile[kp * 2 + 1][n]);
  }
}

#define RB 1024   // router blocks (4 tokens each)
#define XB 4096   // xcast blocks
#define TB 8192   // blocks per weight transpose

__global__ __launch_bounds__(256) void k_prep(
    const float* __restrict__ x, const float* __restrict__ wr,
    const float* __restrict__ w1, const float* __restrict__ w2,
    int2* __restrict__ topi, float2* __restrict__ topw,
    u16* __restrict__ xb, u16* __restrict__ wt1, u16* __restrict__ wt2) {
  __shared__ float tile[64][65];
  int b = blockIdx.x, t = threadIdx.x;
  if (b < RB) {
    // ---- router: 1 wave per token ----
    int wid = t >> 6, lane = t & 63;
    int n = b * 4 + wid;
    const float* xr = x + (size_t)n * CDIM;
    float acc[NEXP];
#pragma unroll
    for (int e = 0; e < NEXP; ++e) acc[e] = 0.f;
    for (int c = lane; c < CDIM; c += 64) {
      float xv = xr[c];
#pragma unroll
      for (int e = 0; e < NEXP; ++e) acc[e] += xv * wr[e * CDIM + c];
    }
#pragma unroll
    for (int e = 0; e < NEXP; ++e) {
      float v = acc[e];
#pragma unroll
      for (int off = 32; off > 0; off >>= 1) v += __shfl_xor(v, off, 64);
      acc[e] = v;
    }
    if (lane == 0) {
      int i1 = 0; float l1 = acc[0];
#pragma unroll
      for (int e = 1; e < NEXP; ++e) if (acc[e] > l1) { l1 = acc[e]; i1 = e; }
      int i2 = (i1 == 0) ? 1 : 0; float l2 = acc[i2];
#pragma unroll
      for (int e = 0; e < NEXP; ++e)
        if (e != i1 && acc[e] > l2) { l2 = acc[e]; i2 = e; }
      float wa = 1.f / (1.f + __expf(l2 - l1));
      topi[n] = make_int2(i1, i2);
      topw[n] = make_float2(wa, 1.f - wa);
    }
  } else if (b < RB + XB) {
    // ---- x fp32 -> bf16 ----
    int i = (b - RB) * 256 + t;
    float4 v = ((const float4*)x)[i];
    ushort4 o;
    o.x = bf16_rne(v.x); o.y = bf16_rne(v.y); o.z = bf16_rne(v.z); o.w = bf16_rne(v.w);
    ((ushort4*)xb)[i] = o;
  } else if (b < RB + XB + TB) {
    // ---- w1 [E][1024][4096] -> wt1 [E][4096][1024] ----
    int idx = b - (RB + XB);
    int e = idx >> 10, rem = idx & 1023;
    int nb = (rem & 63) * 64, kb = (rem >> 6) * 64;
    transpose_tile(w1 + (size_t)e * CDIM * DDIM, wt1 + (size_t)e * DDIM * CDIM,
                   CDIM, DDIM, kb, nb, t, tile);
  } else {
    // ---- w2 [E][4096][1024] -> wt2 [E][1024][4096] (big-ws path only) ----
    int idx = b - (RB + XB + TB);
    int e = idx >> 10, rem = idx & 1023;
    int nb = (rem & 15) * 64, kb = (rem >> 4) * 64;
    transpose_tile(w2 + (size_t)e * DDIM * CDIM, wt2 + (size_t)e * CDIM * DDIM,
                   DDIM, CDIM, kb, nb, t, tile);
  }
}

// standalone transpose for the small-ws fallback (w2 -> shared wt after gemm1)
__global__ __launch_bounds__(256) void k_transpose_w2(const float* __restrict__ in,
                                                      u16* __restrict__ out) {
  __shared__ float tile[64][65];
  int e = blockIdx.z;
  transpose_tile(in + (size_t)e * DDIM * CDIM, out + (size_t)e * CDIM * DDIM,
                 DDIM, CDIM, blockIdx.y * 64, blockIdx.x * 64, threadIdx.x, tile);
}

// ---------------- bucketing (single block) ----------------
__global__ void k_bucket(const int2* __restrict__ topi, int* __restrict__ ptok,
                         int2* __restrict__ ppos, int* __restrict__ ntiles,
                         int* __restrict__ tile_e, int* __restrict__ tile_b) {
  __shared__ int cnt[NEXP], cur[NEXP];
  int t = threadIdx.x;
  if (t < NEXP) cnt[t] = 0;
  __syncthreads();
  for (int n = t; n < NTOK; n += 1024) {
    int2 tv = topi[n];
    atomicAdd(&cnt[tv.x], 1);
    atomicAdd(&cnt[tv.y], 1);
  }
  __syncthreads();
  if (t == 0) {
    int o = 0, nt = 0;
    for (int e = 0; e < NEXP; ++e) {
      cur[e] = o;
      int cap = (cnt[e] + 127) & ~127;
      for (int tb = 0; tb < cap; tb += 128) { tile_e[nt] = e; tile_b[nt] = o + tb; ++nt; }
      o += cap;
    }
    *ntiles = nt;
  }
  __syncthreads();
  for (int n = t; n < NTOK; n += 1024) {
    int2 tv = topi[n];
    int p0 = atomicAdd(&cur[tv.x], 1); ptok[p0] = n;
    int p1 = atomicAdd(&cur[tv.y], 1); ptok[p1] = n;
    ppos[n] = make_int2(p0, p1);
  }
}

// ---------------- pipelined MFMA GEMM (T3/T4/T5: 3-ring LDS, counted vmcnt) --
// BM=128 (one bucket tile), BN=256, BK=64. 512 threads = 8 waves (2M x 4N).
// LDS: A ring 3x[128][64] + B ring 3x[256][64] bf16 = 144 KiB -> 1 block/CU.
// While computing K-tile t (from ring slot t%3), stage K-tile t+2 into slot
// (t+2)%3; at end of tile t: s_waitcnt vmcnt(6) (6 = gload_lds instrs/K-tile,
// in-order retirement => tile t+1 fully landed) + raw s_barrier. Loads thus
// stay in flight across ~2 K-tiles of compute (never drained mid-loop).
// Swizzle (zero-conflict, measured): LDS slot q of row r holds k-block
// (q-r)&7; fragment read slot = (kk*4+quad+(row&7))&7.
template <int KROW, int KLEN, int NOUT, bool GATHER, bool GELUBIAS, bool COLX>
__global__ __launch_bounds__(512, 2) void k_gemm(
    const u16* __restrict__ A, const u16* __restrict__ WT,
    const float* __restrict__ bias, const int* __restrict__ ntiles,
    const int* __restrict__ tile_e, const int* __restrict__ tile_base,
    const int* __restrict__ ptok, u16* __restrict__ Out) {
  __shared__ __align__(16) u16 As[3 * 128 * 64];
  __shared__ __align__(16) u16 Bs[3 * 256 * 64];

  int tileIdx = COLX ? blockIdx.y : blockIdx.x;
  int colIdx = COLX ? blockIdx.x : blockIdx.y;
  if (tileIdx >= *ntiles) return;  // uniform: whole block exits before any barrier
  int e = tile_e[tileIdx];
  int pairbase = tile_base[tileIdx];
  int colbase = colIdx * 256;
  int kbase = blockIdx.z * KLEN;
  u16* OutZ = Out + (size_t)blockIdx.z * ((size_t)PAIR_CAP * NOUT);

  int t = threadIdx.x;
  int wid = t >> 6, lane = t & 63;
  int quad = lane >> 4, lm = lane & 15, l7 = lane & 7;
  int wm = wid & 1, wn = wid >> 1;          // wave tile: rows wm*64.., cols wn*64..
  int rl = lane >> 3, q = lane & 7;
  int kbl = (q - rl) & 7;                   // k-block this lane fetches for LDS slot q

  const char* Ac = (const char*)A;
  const char* Wc = (const char*)WT;
  uint64_t gA[2], gB[4];
#pragma unroll
  for (int j = 0; j < 2; ++j) {
    int row = j * 64 + wid * 8 + rl;        // 0..127
    int arow = GATHER ? ptok[pairbase + row] : (pairbase + row);
    gA[j] = (uint64_t)arow * (KROW * 2) + (uint64_t)kbase * 2 + (uint64_t)kbl * 16;
  }
#pragma unroll
  for (int j = 0; j < 4; ++j) {
    int crow = colbase + j * 64 + wid * 8 + rl;  // colbase..colbase+255
    gB[j] = ((uint64_t)e * NOUT + crow) * (uint64_t)(KROW * 2) +
            (uint64_t)kbase * 2 + (uint64_t)kbl * 16;
  }

  // one-K-tile stagers (wave-uniform LDS base + lane*16 hardware placement)
  auto stA = [&](int kt, int buf) {
    gload_lds16(Ac + gA[0] + (uint64_t)kt * 128, (void*)&As[buf * 8192 + (wid * 8) * 64]);
    gload_lds16(Ac + gA[1] + (uint64_t)kt * 128, (void*)&As[buf * 8192 + (64 + wid * 8) * 64]);
  };
  auto stB01 = [&](int kt, int buf) {
    gload_lds16(Wc + gB[0] + (uint64_t)kt * 128, (void*)&Bs[buf * 16384 + (wid * 8) * 64]);
    gload_lds16(Wc + gB[1] + (uint64_t)kt * 128, (void*)&Bs[buf * 16384 + (64 + wid * 8) * 64]);
  };
  auto stB23 = [&](int kt, int buf) {
    gload_lds16(Wc + gB[2] + (uint64_t)kt * 128, (void*)&Bs[buf * 16384 + (128 + wid * 8) * 64]);
    gload_lds16(Wc + gB[3] + (uint64_t)kt * 128, (void*)&Bs[buf * 16384 + (192 + wid * 8) * 64]);
  };

  f32x4 acc[4][4];
  f32x4 zed = {0.f, 0.f, 0.f, 0.f};
#pragma unroll
  for (int a = 0; a < 4; ++a)
#pragma unroll
    for (int b = 0; b < 4; ++b) acc[a][b] = zed;

  constexpr int NT = KLEN / 64;
  // prologue: stage K-tiles 0,1; wait only K0 (vmcnt(6) leaves K1 in flight)
  stA(0, 0); stB01(0, 0); stB23(0, 0);
  stA(1, 1); stB01(1, 1); stB23(1, 1);
  asm volatile("s_waitcnt vmcnt(6)" ::: "memory");
  __builtin_amdgcn_s_barrier();

  int cb = 0;
  for (int kt = 0; kt < NT; ++kt) {
    int nb = cb + 2; if (nb >= 3) nb -= 3;
    const u16* Ab = &As[cb * 8192];
    const u16* Bb = &Bs[cb * 16384];
    bool st = (kt + 2 < NT);

    bf16x8 af[4], bfr[4];
    // ---- phase 0: kk = 0 ----
#pragma unroll
    for (int m = 0; m < 4; ++m)
      af[m] = ldfrag(&Ab[(wm * 64 + m * 16 + lm) * 64 + ((quad + l7) & 7) * 8]);
#pragma unroll
    for (int n = 0; n < 4; ++n)
      bfr[n] = ldfrag(&Bb[(wn * 64 + n * 16 + lm) * 64 + ((quad + l7) & 7) * 8]);
    if (st) { stA(kt + 2, nb); stB01(kt + 2, nb); }
    __builtin_amdgcn_sched_barrier(0);
    __builtin_amdgcn_s_barrier();
    __builtin_amdgcn_s_setprio(1);
#pragma unroll
    for (int m = 0; m < 4; ++m)
#pragma unroll
      for (int n = 0; n < 4; ++n)
        acc[m][n] = __builtin_amdgcn_mfma_f32_16x16x32_bf16(af[m], bfr[n], acc[m][n], 0, 0, 0);
    __builtin_amdgcn_s_setprio(0);
    __builtin_amdgcn_sched_barrier(0);
    __builtin_amdgcn_s_barrier();
    // ---- phase 1: kk = 1 ----
#pragma unroll
    for (int m = 0; m < 4; ++m)
      af[m] = ldfrag(&Ab[(wm * 64 + m * 16 + lm) * 64 + ((4 + quad + l7) & 7) * 8]);
#pragma unroll
    for (int n = 0; n < 4; ++n)
      bfr[n] = ldfrag(&Bb[(wn * 64 + n * 16 + lm) * 64 + ((4 + quad + l7) & 7) * 8]);
    if (st) { stB23(kt + 2, nb); }
    __builtin_amdgcn_sched_barrier(0);
    __builtin_amdgcn_s_barrier();
    __builtin_amdgcn_s_setprio(1);
#pragma unroll
    for (int m = 0; m < 4; ++m)
#pragma unroll
      for (int n = 0; n < 4; ++n)
        acc[m][n] = __builtin_amdgcn_mfma_f32_16x16x32_bf16(af[m], bfr[n], acc[m][n], 0, 0, 0);
    __builtin_amdgcn_s_setprio(0);
    __builtin_amdgcn_sched_barrier(0);
    // end of K-tile: counted wait (tile kt+1 landed; kt+2 stays in flight)
    if (st) {
      asm volatile("s_waitcnt vmcnt(6)" ::: "memory");
    } else if (kt + 1 < NT) {
      asm volatile("s_waitcnt vmcnt(0)" ::: "memory");  // tail drain
    }
    __builtin_amdgcn_s_barrier();
    cb = cb + 1; if (cb >= 3) cb = 0;
  }

  // epilogue. C/D layout: col=lane&15, row=quad*4+i
#pragma unroll
  for (int tn = 0; tn < 4; ++tn) {
    int col = colbase + wn * 64 + tn * 16 + lm;
    float bv = 0.f;
    if constexpr (GELUBIAS) bv = bias[e * NOUT + col];
#pragma unroll
    for (int tm = 0; tm < 4; ++tm) {
      int row0 = pairbase + wm * 64 + tm * 16 + quad * 4;
#pragma unroll
      for (int i = 0; i < 4; ++i) {
        float vv = acc[tm][tn][i];
        if constexpr (GELUBIAS) vv = gelu_f(vv + bv);
        OutZ[(size_t)(row0 + i) * NOUT + col] = bf16_rne(vv);
      }
    }
  }
}

// ---------------- combine: out[n] = sum_k w_k * (sum_parts P[p_k] + b2[e_k]) --
__global__ __launch_bounds__(256) void k_combine(
    const u16* __restrict__ P, const float2* __restrict__ topw,
    const int2* __restrict__ ppos, const int2* __restrict__ topi,
    const float* __restrict__ b2, float* __restrict__ out, int nparts) {
  int n = blockIdx.x, t = threadIdx.x;
  int2 p = ppos[n];
  float2 w = topw[n];
  int2 ei = topi[n];
  ushort4 a0 = ((const ushort4*)(P + (size_t)p.x * CDIM))[t];
  ushort4 b0 = ((const ushort4*)(P + (size_t)p.y * CDIM))[t];
  float ax = bf2f(a0.x), ay = bf2f(a0.y), az = bf2f(a0.z), aw = bf2f(a0.w);
  float bx = bf2f(b0.x), by = bf2f(b0.y), bz = bf2f(b0.z), bw = bf2f(b0.w);
  if (nparts == 2) {
    const u16* P1 = P + (size_t)PAIR_CAP * CDIM;
    ushort4 a1 = ((const ushort4*)(P1 + (size_t)p.x * CDIM))[t];
    ushort4 b1v = ((const ushort4*)(P1 + (size_t)p.y * CDIM))[t];
    ax += bf2f(a1.x); ay += bf2f(a1.y); az += bf2f(a1.z); aw += bf2f(a1.w);
    bx += bf2f(b1v.x); by += bf2f(b1v.y); bz += bf2f(b1v.z); bw += bf2f(b1v.w);
  }
  float4 c0 = ((const float4*)(b2 + (size_t)ei.x * CDIM))[t];
  float4 c1 = ((const float4*)(b2 + (size_t)ei.y * CDIM))[t];
  float4 o;
  o.x = w.x * (ax + c0.x) + w.y * (bx + c1.x);
  o.y = w.x * (ay + c0.y) + w.y * (by + c1.y);
  o.z = w.x * (az + c0.z) + w.y * (bz + c1.z);
  o.w = w.x * (aw + c0.w) + w.y * (bw + c1.w);
  ((float4*)(out + (size_t)n * CDIM))[t] = o;
}

// ---------------- launch ----------------
extern "C" void kernel_launch(void* const* d_in, const int* in_sizes, int n_in,
                              void* d_out, int out_size, void* d_ws, size_t ws_size,
                              hipStream_t stream) {
  const float* x  = (const float*)d_in[0];
  const float* wr = (const float*)d_in[1];
  const float* w1 = (const float*)d_in[2];
  const float* b1 = (const float*)d_in[3];
  const float* w2 = (const float*)d_in[4];
  const float* b2 = (const float*)d_in[5];
  float* out = (float*)d_out;
  char* ws = (char*)d_ws;

  // ws layout (unchanged):
  //   [0,1024)       ntiles/tile_e/tile_b
  //   topi 32K, topw 32K, ppos 32K, ptok 36K        -> end 136192
  //   xb   8,388,608                                 -> end 8,524,800
  //   h    75,497,472                                -> end 84,022,272
  //   wt1  67,108,864                                -> end 151,131,136
  // big  (ws >= 218,240,000): wt2 67,108,864         -> end 218,240,000
  //       split-K partials (37,748,736) overlay wt1 (dead after gemm1)
  // small (proven 170,005,504): wt1 shared for w2; pairout 18,874,368 at
  //       151,131,136 -> end 170,005,504
  int*    ntiles = (int*)(ws + 192);
  int*    tile_e = (int*)(ws + 256);
  int*    tile_b = (int*)(ws + 640);
  int2*   topi   = (int2*)(ws + 1024);
  float2* topw   = (float2*)(ws + 33792);
  int2*   ppos   = (int2*)(ws + 66560);
  int*    ptok   = (int*)(ws + 99328);
  u16*    xb     = (u16*)(ws + 136192);
  u16*    h      = (u16*)(ws + 8524800);
  u16*    wt1    = (u16*)(ws + 84022272);
  u16*    wt2    = (u16*)(ws + 151131136);
  u16*    parts  = (u16*)(ws + 84022272);   // overlays wt1 (big path)
  u16*    pairout= (u16*)(ws + 151131136);  // small path

  bool big = ws_size >= 218240000ULL;

  hipMemsetAsync(ws + 99328, 0, 36864, stream);  // ptok: pad rows -> token 0

  k_prep<<<big ? (RB + XB + 2 * TB) : (RB + XB + TB), 256, 0, stream>>>(
      x, wr, w1, w2, topi, topw, xb, wt1, wt2);
  k_bucket<<<1, 1024, 0, stream>>>(topi, ptok, ppos, ntiles, tile_e, tile_b);

  // gemm1: [9216x1024] x [1024x4096] per expert; BN=256 -> 16 col blocks
  k_gemm<CDIM, CDIM, DDIM, true, true, false>
      <<<dim3(MAXTILE, DDIM / 256, 1), 512, 0, stream>>>(
          xb, wt1, b1, ntiles, tile_e, tile_b, ptok, h);

  if (big) {
    // gemm2 split-K z=2: KLEN=2048 -> 4 col x 72 tile x 2 = 576 blocks
    k_gemm<DDIM, DDIM / 2, CDIM, false, false, true>
        <<<dim3(CDIM / 256, MAXTILE, 2), 512, 0, stream>>>(
            h, wt2, nullptr, ntiles, tile_e, tile_b, ptok, parts);
    k_combine<<<NTOK, 256, 0, stream>>>(parts, topw, ppos, topi, b2, out, 2);
  } else {
    k_transpose_w2<<<dim3(CDIM / 64, DDIM / 64, NEXP), 256, 0, stream>>>(w2, wt1);
    k_gemm<DDIM, DDIM, CDIM, false, false, true>
        <<<dim3(CDIM / 256, MAXTILE, 1), 512, 0, stream>>>(
            h, wt1, nullptr, ntiles, tile_e, tile_b, ptok, pairout);
    k_combine<<<NTOK, 256, 0, stream>>>(pairout, topw, ppos, topi, b2, out, 1);
  }
}